// Round 5
// baseline (131.408 us; speedup 1.0000x reference)
//
#include <hip/hip_runtime.h>
#include <math.h>

#define IMG   512
#define NIMG  48
#define TB    32            // output tile rows
#define TC    32            // output tile cols
#define SR    42            // staged rows   = TB + 10
#define SC    42            // staged cols   = TC + 10
#define SPW   44            // staged row pitch (words)
#define C1v   1.0e-4f       // 0.01^2
#define C2v   9.0e-4f       // 0.03^2

struct Win { float w[11]; };

// R5: no loop-carried register ring (R3/R4's RMW ring was spill-sabotaged by
// the allocator: VGPR 48-52 < 55 live -> ~2x VALU fat). Three-phase per tile:
//   1) stage raw 42x42 halo (zeros outside image -> padding propagates, no
//      uniform branches downstream),
//   2) H-pass 42x32 h-stat rows into LDS (22 imm-offset ds_read + 88 VALU each),
//   3) V-pass: thread owns 4 CONSECUTIVE output rows x 1 col -> the 14-row
//      stat window is shared: 70 ds_read + 220 FMA per 4 outputs.
// All per-thread arrays are 4-5 elems, statically indexed, fully unrolled.
__global__ __launch_bounds__(256) void ssim_kernel(
        const float* __restrict__ pred,
        const float* __restrict__ targ,
        float* __restrict__ partial, Win win) {
    __shared__ float rp[SR][SPW];          // raw pred tile
    __shared__ float rt[SR][SPW];          // raw target tile
    __shared__ float hs[5][SR][TC];        // h-filtered stats
    __shared__ float wavesum[4];

    const int tid = threadIdx.x;
    const int n   = blockIdx.z;
    const int y0  = blockIdx.y * TB;
    const int x0  = blockIdx.x * TC;

    const float* __restrict__ P = pred + (size_t)n * IMG * IMG;
    const float* __restrict__ T = targ + (size_t)n * IMG * IMG;

    // ---- phase 1: stage raw halo tile, zero-filled outside the image ----
    #pragma unroll 1
    for (int idx = tid; idx < SR * SPW; idx += 256) {
        const int r  = idx / SPW;               // const-div -> magic mul
        const int c  = idx - r * SPW;
        const int gy = y0 - 5 + r;
        const int gx = x0 - 5 + c;
        float p = 0.f, t = 0.f;
        if ((c < SC) & (gy >= 0) & (gy < IMG) & (gx >= 0) & (gx < IMG)) {
            const int g = gy * IMG + gx;
            p = P[g];
            t = T[g];
        }
        rp[r][c] = p;
        rt[r][c] = t;
    }
    __syncthreads();

    // ---- phase 2: horizontal 11-tap stats (42 x 32), pow-2 index split ----
    #pragma unroll 1
    for (int idx = tid; idx < SR * TC; idx += 256) {
        const int r = idx >> 5;
        const int c = idx & 31;
        float h1 = 0.f, h2 = 0.f, hx = 0.f, hy = 0.f, hz = 0.f;
        #pragma unroll
        for (int j = 0; j < 11; ++j) {          // imm-offset ds_reads
            const float wj = win.w[j];
            const float p  = rp[r][c + j];
            const float t  = rt[r][c + j];
            h1 += wj * p;
            h2 += wj * t;
            hx += wj * (p * p);
            hy += wj * (t * t);
            hz += wj * (p * t);
        }
        hs[0][r][c] = h1;
        hs[1][r][c] = h2;
        hs[2][r][c] = hx;
        hs[3][r][c] = hy;
        hs[4][r][c] = hz;
    }
    __syncthreads();

    // ---- phase 3: vertical 11-tap + SSIM; thread = col tx, rows 4ty..4ty+3 ----
    const int tx = tid & 31;
    const int l0 = (tid >> 5) * 4;              // first owned output row
    float a1[4], a2[4], axx[4], ayy[4], axy[4];
    #pragma unroll
    for (int i = 0; i < 4; ++i) { a1[i]=0.f; a2[i]=0.f; axx[i]=0.f; ayy[i]=0.f; axy[i]=0.f; }

    #pragma unroll
    for (int j = 0; j < 14; ++j) {              // h-rows l0..l0+13, imm offsets
        const float v1 = hs[0][l0 + j][tx];
        const float v2 = hs[1][l0 + j][tx];
        const float vx = hs[2][l0 + j][tx];
        const float vy = hs[3][l0 + j][tx];
        const float vz = hs[4][l0 + j][tx];
        #pragma unroll
        for (int i = 0; i < 4; ++i) {           // output l0+i uses taps k=j-i
            const int k = j - i;
            if (k >= 0 && k < 11) {
                const float wk = win.w[k];
                a1[i]  += wk * v1;
                a2[i]  += wk * v2;
                axx[i] += wk * vx;
                ayy[i] += wk * vy;
                axy[i] += wk * vz;
            }
        }
    }

    float acc = 0.f;
    #pragma unroll
    for (int i = 0; i < 4; ++i) {
        const float mu1 = a1[i], mu2 = a2[i];
        const float mu1sq = mu1 * mu1;
        const float mu2sq = mu2 * mu2;
        const float mu12  = mu1 * mu2;
        const float s1  = axx[i] - mu1sq;
        const float s2  = ayy[i] - mu2sq;
        const float s12 = axy[i] - mu12;
        const float num = (2.0f * mu12 + C1v) * (2.0f * s12 + C2v);
        const float den = (mu1sq + mu2sq + C1v) * (s1 + s2 + C2v);
        acc += num * __builtin_amdgcn_rcpf(den);
    }

    // ---- block reduction ----
    #pragma unroll
    for (int off = 32; off > 0; off >>= 1)
        acc += __shfl_down(acc, off, 64);
    const int wv = tid >> 6;
    if ((tid & 63) == 0) wavesum[wv] = acc;
    __syncthreads();
    if (tid == 0) {
        const int bid = (blockIdx.z * gridDim.y + blockIdx.y) * gridDim.x + blockIdx.x;
        partial[bid] = wavesum[0] + wavesum[1] + wavesum[2] + wavesum[3];
    }
}

__global__ __launch_bounds__(256) void ssim_reduce_kernel(
        const float* __restrict__ partial,
        float* __restrict__ out,
        int nblk, double inv_n) {
    __shared__ double wsum[4];
    double s = 0.0;
    for (int i = threadIdx.x; i < nblk; i += 256)
        s += (double)partial[i];
    #pragma unroll
    for (int off = 32; off > 0; off >>= 1)
        s += __shfl_down(s, off, 64);
    const int wv = threadIdx.x >> 6;
    if ((threadIdx.x & 63) == 0) wsum[wv] = s;
    __syncthreads();
    if (threadIdx.x == 0) {
        const double tot = wsum[0] + wsum[1] + wsum[2] + wsum[3];
        out[0] = (float)(tot * inv_n);
    }
}

extern "C" void kernel_launch(void* const* d_in, const int* in_sizes, int n_in,
                              void* d_out, int out_size, void* d_ws, size_t ws_size,
                              hipStream_t stream) {
    const float* pred = (const float*)d_in[0];
    const float* targ = (const float*)d_in[1];
    float* out     = (float*)d_out;
    float* partial = (float*)d_ws;   // 16*16*48 = 12288 floats, all written

    Win win;
    {
        double v[11], s = 0.0;
        for (int i = 0; i < 11; ++i) {
            float d   = (float)i - 5.0f;
            float arg = -(d * d) / 4.5f;      // 2*sigma^2 = 4.5
            v[i] = exp((double)arg);
            s += v[i];
        }
        for (int i = 0; i < 11; ++i) win.w[i] = (float)(v[i] / s);
    }

    dim3 grid(IMG / TC, IMG / TB, NIMG);      // (16, 16, 48) = 12288 blocks
    ssim_kernel<<<grid, 256, 0, stream>>>(pred, targ, partial, win);

    const int nblk = (IMG / TC) * (IMG / TB) * NIMG;
    const double inv_n = 1.0 / ((double)NIMG * IMG * IMG);
    ssim_reduce_kernel<<<1, 256, 0, stream>>>(partial, out, nblk, inv_n);
}

// Round 6
// 102.394 us; speedup vs baseline: 1.2834x; 1.2834x over previous
//
#include <hip/hip_runtime.h>
#include <math.h>

#define IMG   512
#define NIMG  48
#define TB    64            // output tile rows
#define TC    32            // output tile cols
#define SR    74            // staged/h-stat rows = TB + 10
#define SPW   48            // staged words per row: global cols [x0-8, x0+39]
#define NF4   12            // float4 chunks per staged row
#define C1v   1.0e-4f       // 0.01^2
#define C2v   9.0e-4f       // 0.03^2

struct Win { float w[11]; };

// R6: the LDS pipe (not VALU) was the R1-R5 bottleneck (~105us of b32 traffic).
// All LDS ops are now b128:
//  phase1: aligned float4 global loads -> b128 stores. Stage [x0-8,x0+39] so
//          every 16B chunk is fully in-image or fully padding (uniform zero).
//  phase2: thread = 4 consecutive h-cols of one row: 10 rd + 5 wr b128 per
//          4 elements (was 88+20 b32). 8 lanes = contiguous 128B, no conflict.
//  phase3: thread = 2 rows x 4 cols: 60 b128 per 8 outputs, 12-row window
//          register-shared, stats as float4 lanes.
__global__ __launch_bounds__(256, 4) void ssim_kernel(
        const float* __restrict__ pred,
        const float* __restrict__ targ,
        float* __restrict__ partial, Win win) {
    __shared__ float rp[SR][SPW];
    __shared__ float rt[SR][SPW];
    __shared__ float hs[5][SR][TC];
    __shared__ float wavesum[4];

    const int tid = threadIdx.x;
    const int n   = blockIdx.z;
    const int by  = blockIdx.y;
    const int bx  = blockIdx.x;
    const int y0  = by * TB;
    const int x0  = bx * TC;

    const float* __restrict__ P = pred + (size_t)n * IMG * IMG;
    const float* __restrict__ T = targ + (size_t)n * IMG * IMG;

    // ---- phase 1: stage halo tile as float4 chunks, zero-filled padding ----
    #pragma unroll 1
    for (int idx = tid; idx < SR * NF4; idx += 256) {
        const int r  = idx / NF4;
        const int c4 = idx - r * NF4;
        const int gy = y0 - 5 + r;
        // chunk is fully OOB (padding) or fully in-image -- never partial
        const bool zero = (gy < 0) | (gy >= IMG) |
                          ((bx == 0) & (c4 < 2)) | ((bx == 15) & (c4 >= 10));
        float4 p = make_float4(0.f, 0.f, 0.f, 0.f);
        float4 t = make_float4(0.f, 0.f, 0.f, 0.f);
        if (!zero) {
            const int g = gy * IMG + (x0 - 8 + 4 * c4);
            p = *(const float4*)(P + g);
            t = *(const float4*)(T + g);
        }
        *(float4*)&rp[r][4 * c4] = p;
        *(float4*)&rt[r][4 * c4] = t;
    }
    __syncthreads();

    // ---- phase 2: H-pass, 4 consecutive cols per thread ----
    // output col x0+4cb+i (i=0..3) tap j reads staged word 4cb + (i+j+3)
    #pragma unroll 1
    for (int idx = tid; idx < SR * 8; idx += 256) {
        const int r  = idx >> 3;
        const int cb = idx & 7;
        float a[20], b[20];
        #pragma unroll
        for (int k = 0; k < 5; ++k) {
            const float4 pa = *(const float4*)&rp[r][4 * cb + 4 * k];
            const float4 pb = *(const float4*)&rt[r][4 * cb + 4 * k];
            a[4*k+0] = pa.x; a[4*k+1] = pa.y; a[4*k+2] = pa.z; a[4*k+3] = pa.w;
            b[4*k+0] = pb.x; b[4*k+1] = pb.y; b[4*k+2] = pb.z; b[4*k+3] = pb.w;
        }
        float s1[4], s2[4], sx[4], sy[4], sz[4];
        #pragma unroll
        for (int i = 0; i < 4; ++i) { s1[i]=0.f; s2[i]=0.f; sx[i]=0.f; sy[i]=0.f; sz[i]=0.f; }
        #pragma unroll
        for (int m = 3; m <= 16; ++m) {       // products once per window col
            const float p  = a[m];
            const float t  = b[m];
            const float pp = p * p;
            const float tt = t * t;
            const float pt = p * t;
            #pragma unroll
            for (int i = 0; i < 4; ++i) {
                const int j = m - 3 - i;
                if (j >= 0 && j < 11) {
                    const float wj = win.w[j];
                    s1[i] += wj * p;
                    s2[i] += wj * t;
                    sx[i] += wj * pp;
                    sy[i] += wj * tt;
                    sz[i] += wj * pt;
                }
            }
        }
        *(float4*)&hs[0][r][4 * cb] = make_float4(s1[0], s1[1], s1[2], s1[3]);
        *(float4*)&hs[1][r][4 * cb] = make_float4(s2[0], s2[1], s2[2], s2[3]);
        *(float4*)&hs[2][r][4 * cb] = make_float4(sx[0], sx[1], sx[2], sx[3]);
        *(float4*)&hs[3][r][4 * cb] = make_float4(sy[0], sy[1], sy[2], sy[3]);
        *(float4*)&hs[4][r][4 * cb] = make_float4(sz[0], sz[1], sz[2], sz[3]);
    }
    __syncthreads();

    // ---- phase 3: V-pass, thread = 2 consecutive rows x 4 cols ----
    const int pr = tid >> 3;            // row pair 0..31 -> rows 2pr, 2pr+1
    const int cb = tid & 7;
    const int l0 = 2 * pr;
    float a0[5][4], a1[5][4];
    #pragma unroll
    for (int s = 0; s < 5; ++s)
        #pragma unroll
        for (int c = 0; c < 4; ++c) { a0[s][c] = 0.f; a1[s][c] = 0.f; }

    #pragma unroll
    for (int j = 0; j < 12; ++j) {      // h-rows l0..l0+11
        #pragma unroll
        for (int s = 0; s < 5; ++s) {
            const float4 v = *(const float4*)&hs[s][l0 + j][4 * cb];
            const float vv[4] = { v.x, v.y, v.z, v.w };
            if (j < 11) {
                const float wj = win.w[j];
                #pragma unroll
                for (int c = 0; c < 4; ++c) a0[s][c] += wj * vv[c];
            }
            if (j >= 1) {
                const float wj = win.w[j - 1];
                #pragma unroll
                for (int c = 0; c < 4; ++c) a1[s][c] += wj * vv[c];
            }
        }
    }

    float acc = 0.f;
    #pragma unroll
    for (int k = 0; k < 2; ++k) {
        #pragma unroll
        for (int c = 0; c < 4; ++c) {
            const float mu1 = k ? a1[0][c] : a0[0][c];
            const float mu2 = k ? a1[1][c] : a0[1][c];
            const float exx = k ? a1[2][c] : a0[2][c];
            const float eyy = k ? a1[3][c] : a0[3][c];
            const float exy = k ? a1[4][c] : a0[4][c];
            const float mu1sq = mu1 * mu1;
            const float mu2sq = mu2 * mu2;
            const float mu12  = mu1 * mu2;
            const float sg1 = exx - mu1sq;
            const float sg2 = eyy - mu2sq;
            const float sgx = exy - mu12;
            const float num = (2.0f * mu12 + C1v) * (2.0f * sgx + C2v);
            const float den = (mu1sq + mu2sq + C1v) * (sg1 + sg2 + C2v);
            acc += num * __builtin_amdgcn_rcpf(den);
        }
    }

    // ---- block reduction ----
    #pragma unroll
    for (int off = 32; off > 0; off >>= 1)
        acc += __shfl_down(acc, off, 64);
    const int wv = tid >> 6;
    if ((tid & 63) == 0) wavesum[wv] = acc;
    __syncthreads();
    if (tid == 0) {
        const int bid = (blockIdx.z * gridDim.y + blockIdx.y) * gridDim.x + blockIdx.x;
        partial[bid] = wavesum[0] + wavesum[1] + wavesum[2] + wavesum[3];
    }
}

__global__ __launch_bounds__(256) void ssim_reduce_kernel(
        const float* __restrict__ partial,
        float* __restrict__ out,
        int nblk, double inv_n) {
    __shared__ double wsum[4];
    double s = 0.0;
    for (int i = threadIdx.x; i < nblk; i += 256)
        s += (double)partial[i];
    #pragma unroll
    for (int off = 32; off > 0; off >>= 1)
        s += __shfl_down(s, off, 64);
    const int wv = threadIdx.x >> 6;
    if ((threadIdx.x & 63) == 0) wsum[wv] = s;
    __syncthreads();
    if (threadIdx.x == 0) {
        const double tot = wsum[0] + wsum[1] + wsum[2] + wsum[3];
        out[0] = (float)(tot * inv_n);
    }
}

extern "C" void kernel_launch(void* const* d_in, const int* in_sizes, int n_in,
                              void* d_out, int out_size, void* d_ws, size_t ws_size,
                              hipStream_t stream) {
    const float* pred = (const float*)d_in[0];
    const float* targ = (const float*)d_in[1];
    float* out     = (float*)d_out;
    float* partial = (float*)d_ws;   // 16*8*48 = 6144 floats, all written

    Win win;
    {
        double v[11], s = 0.0;
        for (int i = 0; i < 11; ++i) {
            float d   = (float)i - 5.0f;
            float arg = -(d * d) / 4.5f;      // 2*sigma^2 = 4.5
            v[i] = exp((double)arg);
            s += v[i];
        }
        for (int i = 0; i < 11; ++i) win.w[i] = (float)(v[i] / s);
    }

    dim3 grid(IMG / TC, IMG / TB, NIMG);      // (16, 8, 48) = 6144 blocks
    ssim_kernel<<<grid, 256, 0, stream>>>(pred, targ, partial, win);

    const int nblk = (IMG / TC) * (IMG / TB) * NIMG;
    const double inv_n = 1.0 / ((double)NIMG * IMG * IMG);
    ssim_reduce_kernel<<<1, 256, 0, stream>>>(partial, out, nblk, inv_n);
}

// Round 7
// 95.140 us; speedup vs baseline: 1.3812x; 1.0762x over previous
//
#include <hip/hip_runtime.h>
#include <math.h>

#define IMG   512
#define NIMG  48
#define TB    64            // output tile rows
#define TC    32            // output tile cols
#define SR    74            // h-stat rows = TB + 10
#define HP    36            // hs row pitch (words): 32 + 4 -> 4-bank shift/row,
                            // kills the pitch-32 "bank = column only" 8-way alias
#define C1v   1.0e-4f       // 0.01^2
#define C2v   9.0e-4f       // 0.03^2

struct Win { float w[11]; };

// R7: R6's 16.3M bank conflicts came from hs pitch 32 (bank depends only on
// column -> 8-way alias across a wave's 8 row-groups) and rp/rt pitch 48
// (4-way). Fixes: (1) hs pitch 36; (2) raw staging DELETED -- phase A computes
// h-stats directly from 10 aligned float4 global loads per thread (halo
// overlap is L1-served), removing 1776 LDS writes + 5920 LDS reads + a
// barrier per block and 30KB of LDS (53.3KB total -> 3 blocks/CU).
__global__ __launch_bounds__(256, 4) void ssim_kernel(
        const float* __restrict__ pred,
        const float* __restrict__ targ,
        float* __restrict__ partial, Win win) {
    __shared__ float hs[5][SR][HP];
    __shared__ float wavesum[4];

    const int tid = threadIdx.x;
    const int n   = blockIdx.z;
    const int by  = blockIdx.y;
    const int bx  = blockIdx.x;
    const int y0  = by * TB;
    const int x0  = bx * TC;

    const float* __restrict__ P = pred + (size_t)n * IMG * IMG;
    const float* __restrict__ T = targ + (size_t)n * IMG * IMG;

    // ---- phase A: H-pass straight from global; thread = 4 h-cols x 1 row ----
    // chunks k=0..4 cover global cols x0 + 4*(cb+k-2) .. +3  (16B aligned)
    #pragma unroll 1
    for (int idx = tid; idx < SR * 8; idx += 256) {
        const int r  = idx >> 3;
        const int cb = idx & 7;
        const int gy = y0 - 5 + r;
        const bool yok = (gy >= 0) & (gy < IMG);
        const float* __restrict__ Prow = P + (long)gy * IMG;
        const float* __restrict__ Trow = T + (long)gy * IMG;

        float a[20], b[20];
        #pragma unroll
        for (int k = 0; k < 5; ++k) {
            // fully-in-image or fully-padding per 16B chunk, never partial
            const bool zero = (!yok) |
                              ((bx == 0)  & (cb + k <= 1)) |
                              ((bx == 15) & (cb + k >= 10));
            float4 p = make_float4(0.f, 0.f, 0.f, 0.f);
            float4 t = make_float4(0.f, 0.f, 0.f, 0.f);
            if (!zero) {
                const int gx = x0 + 4 * (cb + k - 2);
                p = *(const float4*)(Prow + gx);
                t = *(const float4*)(Trow + gx);
            }
            a[4*k+0] = p.x; a[4*k+1] = p.y; a[4*k+2] = p.z; a[4*k+3] = p.w;
            b[4*k+0] = t.x; b[4*k+1] = t.y; b[4*k+2] = t.z; b[4*k+3] = t.w;
        }

        float s1[4], s2[4], sx[4], sy[4], sz[4];
        #pragma unroll
        for (int i = 0; i < 4; ++i) { s1[i]=0.f; s2[i]=0.f; sx[i]=0.f; sy[i]=0.f; sz[i]=0.f; }
        #pragma unroll
        for (int m = 3; m <= 16; ++m) {       // products once per window col
            const float p  = a[m];
            const float t  = b[m];
            const float pp = p * p;
            const float tt = t * t;
            const float pt = p * t;
            #pragma unroll
            for (int i = 0; i < 4; ++i) {     // output col i uses tap j = m-3-i
                const int j = m - 3 - i;
                if (j >= 0 && j < 11) {
                    const float wj = win.w[j];
                    s1[i] += wj * p;
                    s2[i] += wj * t;
                    sx[i] += wj * pp;
                    sy[i] += wj * tt;
                    sz[i] += wj * pt;
                }
            }
        }
        *(float4*)&hs[0][r][4 * cb] = make_float4(s1[0], s1[1], s1[2], s1[3]);
        *(float4*)&hs[1][r][4 * cb] = make_float4(s2[0], s2[1], s2[2], s2[3]);
        *(float4*)&hs[2][r][4 * cb] = make_float4(sx[0], sx[1], sx[2], sx[3]);
        *(float4*)&hs[3][r][4 * cb] = make_float4(sy[0], sy[1], sy[2], sy[3]);
        *(float4*)&hs[4][r][4 * cb] = make_float4(sz[0], sz[1], sz[2], sz[3]);
    }
    __syncthreads();

    // ---- phase B: V-pass, thread = 2 consecutive rows x 4 cols ----
    const int pr = tid >> 3;            // row pair 0..31 -> rows 2pr, 2pr+1
    const int cb = tid & 7;
    const int l0 = 2 * pr;
    float a0[5][4], a1[5][4];
    #pragma unroll
    for (int s = 0; s < 5; ++s)
        #pragma unroll
        for (int c = 0; c < 4; ++c) { a0[s][c] = 0.f; a1[s][c] = 0.f; }

    #pragma unroll
    for (int j = 0; j < 12; ++j) {      // h-rows l0..l0+11
        #pragma unroll
        for (int s = 0; s < 5; ++s) {
            const float4 v = *(const float4*)&hs[s][l0 + j][4 * cb];
            const float vv[4] = { v.x, v.y, v.z, v.w };
            if (j < 11) {
                const float wj = win.w[j];
                #pragma unroll
                for (int c = 0; c < 4; ++c) a0[s][c] += wj * vv[c];
            }
            if (j >= 1) {
                const float wj = win.w[j - 1];
                #pragma unroll
                for (int c = 0; c < 4; ++c) a1[s][c] += wj * vv[c];
            }
        }
    }

    float acc = 0.f;
    #pragma unroll
    for (int k = 0; k < 2; ++k) {
        #pragma unroll
        for (int c = 0; c < 4; ++c) {
            const float mu1 = k ? a1[0][c] : a0[0][c];
            const float mu2 = k ? a1[1][c] : a0[1][c];
            const float exx = k ? a1[2][c] : a0[2][c];
            const float eyy = k ? a1[3][c] : a0[3][c];
            const float exy = k ? a1[4][c] : a0[4][c];
            const float mu1sq = mu1 * mu1;
            const float mu2sq = mu2 * mu2;
            const float mu12  = mu1 * mu2;
            const float sg1 = exx - mu1sq;
            const float sg2 = eyy - mu2sq;
            const float sgx = exy - mu12;
            const float num = (2.0f * mu12 + C1v) * (2.0f * sgx + C2v);
            const float den = (mu1sq + mu2sq + C1v) * (sg1 + sg2 + C2v);
            acc += num * __builtin_amdgcn_rcpf(den);
        }
    }

    // ---- block reduction ----
    #pragma unroll
    for (int off = 32; off > 0; off >>= 1)
        acc += __shfl_down(acc, off, 64);
    const int wv = tid >> 6;
    if ((tid & 63) == 0) wavesum[wv] = acc;
    __syncthreads();
    if (tid == 0) {
        const int bid = (blockIdx.z * gridDim.y + blockIdx.y) * gridDim.x + blockIdx.x;
        partial[bid] = wavesum[0] + wavesum[1] + wavesum[2] + wavesum[3];
    }
}

__global__ __launch_bounds__(256) void ssim_reduce_kernel(
        const float* __restrict__ partial,
        float* __restrict__ out,
        int nblk, double inv_n) {
    __shared__ double wsum[4];
    double s = 0.0;
    for (int i = threadIdx.x; i < nblk; i += 256)
        s += (double)partial[i];
    #pragma unroll
    for (int off = 32; off > 0; off >>= 1)
        s += __shfl_down(s, off, 64);
    const int wv = threadIdx.x >> 6;
    if ((threadIdx.x & 63) == 0) wsum[wv] = s;
    __syncthreads();
    if (threadIdx.x == 0) {
        const double tot = wsum[0] + wsum[1] + wsum[2] + wsum[3];
        out[0] = (float)(tot * inv_n);
    }
}

extern "C" void kernel_launch(void* const* d_in, const int* in_sizes, int n_in,
                              void* d_out, int out_size, void* d_ws, size_t ws_size,
                              hipStream_t stream) {
    const float* pred = (const float*)d_in[0];
    const float* targ = (const float*)d_in[1];
    float* out     = (float*)d_out;
    float* partial = (float*)d_ws;   // 16*8*48 = 6144 floats, all written

    Win win;
    {
        double v[11], s = 0.0;
        for (int i = 0; i < 11; ++i) {
            float d   = (float)i - 5.0f;
            float arg = -(d * d) / 4.5f;      // 2*sigma^2 = 4.5
            v[i] = exp((double)arg);
            s += v[i];
        }
        for (int i = 0; i < 11; ++i) win.w[i] = (float)(v[i] / s);
    }

    dim3 grid(IMG / TC, IMG / TB, NIMG);      // (16, 8, 48) = 6144 blocks
    ssim_kernel<<<grid, 256, 0, stream>>>(pred, targ, partial, win);

    const int nblk = (IMG / TC) * (IMG / TB) * NIMG;
    const double inv_n = 1.0 / ((double)NIMG * IMG * IMG);
    ssim_reduce_kernel<<<1, 256, 0, stream>>>(partial, out, nblk, inv_n);
}

// Round 8
// 77.518 us; speedup vs baseline: 1.6952x; 1.2273x over previous
//
#include <hip/hip_runtime.h>
#include <math.h>

#define IMG   512
#define NIMG  48
#define TB    64            // output tile rows
#define TC    32            // output tile cols
#define SR    74            // h-stat rows = TB + 10
#define HP    32            // hs row pitch (words) -- row drops out of bank calc;
                            // bank-group = swizzled col chunk only
#define C1v   1.0e-4f       // 0.01^2
#define C2v   9.0e-4f       // 0.03^2

struct Win { float w[11]; };

// R8: two changes driven by R7's residual 11.8M conflicts (= exactly +8 cyc on
// each phase-B read; rows-stride-2 + any LINEAR swizzle keeps bank-group
// parity collapsed under mod-4 b128 sub-phasing):
//  1) NON-linear chunk rotation: stat row r stores col-chunk cb at chunk
//     (cb + (r>>1)) & 7. Injects row bit1 into group bit0 -> exactly-even
//     bank-group coverage under consecutive-8/16/32 AND mod-4 interleave
//     phasings, for both the write (row-stride-1) and read (row-stride-2)
//     patterns. Pitch back to 32 (row term vanishes mod 32 banks).
//  2) 4 stats instead of 5: filter s=(x+y), d=(x-y), s^2, d^2. Then
//     2u1u2=(S1^2-S2^2)/2, u1^2+u2^2=(S1^2+S2^2)/2, sig1+sig2=(Q1+Q2)/2-A,
//     2sig12=(Q1-Q2)/2-B. -20% LDS traffic & filter FLOPs; LDS 53.8->37.9KB
//     -> 4 blocks/CU (16 waves, was 8).
__global__ __launch_bounds__(256, 4) void ssim_kernel(
        const float* __restrict__ pred,
        const float* __restrict__ targ,
        float* __restrict__ partial, Win win) {
    __shared__ float hs[4][SR][HP];
    __shared__ float wavesum[4];

    const int tid = threadIdx.x;
    const int n   = blockIdx.z;
    const int by  = blockIdx.y;
    const int bx  = blockIdx.x;
    const int y0  = by * TB;
    const int x0  = bx * TC;

    const float* __restrict__ P = pred + (size_t)n * IMG * IMG;
    const float* __restrict__ T = targ + (size_t)n * IMG * IMG;

    // ---- phase A: H-pass straight from global; thread = 4 h-cols x 1 row ----
    #pragma unroll 1
    for (int idx = tid; idx < SR * 8; idx += 256) {
        const int r  = idx >> 3;
        const int cb = idx & 7;
        const int gy = y0 - 5 + r;
        const bool yok = (gy >= 0) & (gy < IMG);
        const float* __restrict__ Prow = P + (long)gy * IMG;
        const float* __restrict__ Trow = T + (long)gy * IMG;

        float a[20], b[20];
        #pragma unroll
        for (int k = 0; k < 5; ++k) {
            // every 16B chunk is fully in-image or fully padding
            const bool zero = (!yok) |
                              ((bx == 0)  & (cb + k <= 1)) |
                              ((bx == 15) & (cb + k >= 10));
            float4 p = make_float4(0.f, 0.f, 0.f, 0.f);
            float4 t = make_float4(0.f, 0.f, 0.f, 0.f);
            if (!zero) {
                const int gx = x0 + 4 * (cb + k - 2);
                p = *(const float4*)(Prow + gx);
                t = *(const float4*)(Trow + gx);
            }
            a[4*k+0] = p.x; a[4*k+1] = p.y; a[4*k+2] = p.z; a[4*k+3] = p.w;
            b[4*k+0] = t.x; b[4*k+1] = t.y; b[4*k+2] = t.z; b[4*k+3] = t.w;
        }

        float s1[4], s2[4], q1[4], q2[4];
        #pragma unroll
        for (int i = 0; i < 4; ++i) { s1[i]=0.f; s2[i]=0.f; q1[i]=0.f; q2[i]=0.f; }
        #pragma unroll
        for (int m = 3; m <= 16; ++m) {       // sum/diff/squares once per col
            const float sm = a[m] + b[m];
            const float dm = a[m] - b[m];
            const float sq = sm * sm;
            const float dq = dm * dm;
            #pragma unroll
            for (int i = 0; i < 4; ++i) {     // output col i uses tap j = m-3-i
                const int j = m - 3 - i;
                if (j >= 0 && j < 11) {
                    const float wj = win.w[j];
                    s1[i] += wj * sm;
                    s2[i] += wj * dm;
                    q1[i] += wj * sq;
                    q2[i] += wj * dq;
                }
            }
        }
        const int c4 = 4 * ((cb + (r >> 1)) & 7);   // non-linear chunk rotate
        *(float4*)&hs[0][r][c4] = make_float4(s1[0], s1[1], s1[2], s1[3]);
        *(float4*)&hs[1][r][c4] = make_float4(s2[0], s2[1], s2[2], s2[3]);
        *(float4*)&hs[2][r][c4] = make_float4(q1[0], q1[1], q1[2], q1[3]);
        *(float4*)&hs[3][r][c4] = make_float4(q2[0], q2[1], q2[2], q2[3]);
    }
    __syncthreads();

    // ---- phase B: V-pass, thread = 2 consecutive rows x 4 cols ----
    const int pr = tid >> 3;            // row pair 0..31 -> rows 2pr, 2pr+1
    const int cb = tid & 7;
    const int l0 = 2 * pr;
    float a0[4][4], a1[4][4];
    #pragma unroll
    for (int st = 0; st < 4; ++st)
        #pragma unroll
        for (int c = 0; c < 4; ++c) { a0[st][c] = 0.f; a1[st][c] = 0.f; }

    #pragma unroll
    for (int j = 0; j < 12; ++j) {      // h-rows l0..l0+11
        const int row = l0 + j;
        const int c4  = 4 * ((cb + pr + (j >> 1)) & 7);   // (row>>1) = pr+(j>>1)
        #pragma unroll
        for (int st = 0; st < 4; ++st) {
            const float4 v = *(const float4*)&hs[st][row][c4];
            const float vv[4] = { v.x, v.y, v.z, v.w };
            if (j < 11) {
                const float wj = win.w[j];
                #pragma unroll
                for (int c = 0; c < 4; ++c) a0[st][c] += wj * vv[c];
            }
            if (j >= 1) {
                const float wj = win.w[j - 1];
                #pragma unroll
                for (int c = 0; c < 4; ++c) a1[st][c] += wj * vv[c];
            }
        }
    }

    float acc = 0.f;
    #pragma unroll
    for (int k = 0; k < 2; ++k) {
        #pragma unroll
        for (int c = 0; c < 4; ++c) {
            const float S1 = k ? a1[0][c] : a0[0][c];
            const float S2 = k ? a1[1][c] : a0[1][c];
            const float Q1 = k ? a1[2][c] : a0[2][c];
            const float Q2 = k ? a1[3][c] : a0[3][c];
            const float s1q = S1 * S1;
            const float s2q = S2 * S2;
            const float A_  = 0.5f * (s1q + s2q);     // mu1^2 + mu2^2
            const float B_  = 0.5f * (s1q - s2q);     // 2 mu1 mu2
            const float sps = 0.5f * (Q1 + Q2) - A_;  // sig1^2 + sig2^2
            const float sxx = 0.5f * (Q1 - Q2) - B_;  // 2 sig12
            const float num = (B_ + C1v) * (sxx + C2v);
            const float den = (A_ + C1v) * (sps + C2v);
            acc += num * __builtin_amdgcn_rcpf(den);
        }
    }

    // ---- block reduction ----
    #pragma unroll
    for (int off = 32; off > 0; off >>= 1)
        acc += __shfl_down(acc, off, 64);
    const int wv = tid >> 6;
    if ((tid & 63) == 0) wavesum[wv] = acc;
    __syncthreads();
    if (tid == 0) {
        const int bid = (blockIdx.z * gridDim.y + blockIdx.y) * gridDim.x + blockIdx.x;
        partial[bid] = wavesum[0] + wavesum[1] + wavesum[2] + wavesum[3];
    }
}

__global__ __launch_bounds__(256) void ssim_reduce_kernel(
        const float* __restrict__ partial,
        float* __restrict__ out,
        int nblk, double inv_n) {
    __shared__ double wsum[4];
    double s = 0.0;
    for (int i = threadIdx.x; i < nblk; i += 256)
        s += (double)partial[i];
    #pragma unroll
    for (int off = 32; off > 0; off >>= 1)
        s += __shfl_down(s, off, 64);
    const int wv = threadIdx.x >> 6;
    if ((threadIdx.x & 63) == 0) wsum[wv] = s;
    __syncthreads();
    if (threadIdx.x == 0) {
        const double tot = wsum[0] + wsum[1] + wsum[2] + wsum[3];
        out[0] = (float)(tot * inv_n);
    }
}

extern "C" void kernel_launch(void* const* d_in, const int* in_sizes, int n_in,
                              void* d_out, int out_size, void* d_ws, size_t ws_size,
                              hipStream_t stream) {
    const float* pred = (const float*)d_in[0];
    const float* targ = (const float*)d_in[1];
    float* out     = (float*)d_out;
    float* partial = (float*)d_ws;   // 16*8*48 = 6144 floats, all written

    Win win;
    {
        double v[11], s = 0.0;
        for (int i = 0; i < 11; ++i) {
            float d   = (float)i - 5.0f;
            float arg = -(d * d) / 4.5f;      // 2*sigma^2 = 4.5
            v[i] = exp((double)arg);
            s += v[i];
        }
        for (int i = 0; i < 11; ++i) win.w[i] = (float)(v[i] / s);
    }

    dim3 grid(IMG / TC, IMG / TB, NIMG);      // (16, 8, 48) = 6144 blocks
    ssim_kernel<<<grid, 256, 0, stream>>>(pred, targ, partial, win);

    const int nblk = (IMG / TC) * (IMG / TB) * NIMG;
    const double inv_n = 1.0 / ((double)NIMG * IMG * IMG);
    ssim_reduce_kernel<<<1, 256, 0, stream>>>(partial, out, nblk, inv_n);
}

// Round 9
// 71.081 us; speedup vs baseline: 1.8487x; 1.0906x over previous
//
#include <hip/hip_runtime.h>
#include <math.h>

#define IMG   512
#define NIMG  48
#define TB    64            // output tile rows
#define TC    32            // output tile cols
#define SR    74            // stat rows = TB + 10
#define PITCH 77            // words per stat column; ODD -> bank = (13x+r) mod 32
                            // is bijective over 32 lanes (m136-validated b32 model)
#define STS   (TC * PITCH)  // stat plane stride = 2464 words (2464 mod 32 == 0)
#define C1v   1.0e-4f       // 0.01^2
#define C2v   9.0e-4f       // 0.03^2

struct Win { float w[11]; };

// R9: after two falsified b128-phasing swizzles (R7/R8 both measured exactly
// +8 cyc per strided-row wave b128 read), drop b128 V-pass reads entirely.
// Stats stored TRANSPOSED hs[st][x][r] with odd pitch 77:
//   reads:  lane bank = (13x + r) mod 32, bijective over lanes 0..31 ->
//           whole wave hits every bank exactly 2x = b32 minimum (free, m136).
//   writes: bank = (20cb + 13i + r) mod 32 -> exactly 2 lanes/bank (free).
// Phase B is a register sliding window: thread = (col x, 8 output rows),
// 18 imm-offset b32 reads per stat (ds_read2-pairable) + 88 FMA per stat.
__global__ __launch_bounds__(256, 4) void ssim_kernel(
        const float* __restrict__ pred,
        const float* __restrict__ targ,
        float* __restrict__ partial, Win win) {
    __shared__ float hs[4 * STS];
    __shared__ float wavesum[4];

    const int tid = threadIdx.x;
    const int n   = blockIdx.z;
    const int by  = blockIdx.y;
    const int bx  = blockIdx.x;
    const int y0  = by * TB;
    const int x0  = bx * TC;

    const float* __restrict__ P = pred + (size_t)n * IMG * IMG;
    const float* __restrict__ T = targ + (size_t)n * IMG * IMG;

    // ---- phase A: H-pass from global; thread = 4 h-cols x 1 stat row ----
    #pragma unroll 1
    for (int idx = tid; idx < SR * 8; idx += 256) {
        const int r  = idx >> 3;
        const int cb = idx & 7;
        const int gy = y0 - 5 + r;
        const bool yok = (gy >= 0) & (gy < IMG);
        const float* __restrict__ Prow = P + (long)gy * IMG;
        const float* __restrict__ Trow = T + (long)gy * IMG;

        float a[20], b[20];
        #pragma unroll
        for (int k = 0; k < 5; ++k) {
            // every 16B chunk is fully in-image or fully padding (R8-proven)
            const bool zero = (!yok) |
                              ((bx == 0)  & (cb + k <= 1)) |
                              ((bx == 15) & (cb + k >= 10));
            float4 p = make_float4(0.f, 0.f, 0.f, 0.f);
            float4 t = make_float4(0.f, 0.f, 0.f, 0.f);
            if (!zero) {
                const int gx = x0 + 4 * (cb + k - 2);
                p = *(const float4*)(Prow + gx);
                t = *(const float4*)(Trow + gx);
            }
            a[4*k+0] = p.x; a[4*k+1] = p.y; a[4*k+2] = p.z; a[4*k+3] = p.w;
            b[4*k+0] = t.x; b[4*k+1] = t.y; b[4*k+2] = t.z; b[4*k+3] = t.w;
        }

        float s1[4], s2[4], q1[4], q2[4];
        #pragma unroll
        for (int i = 0; i < 4; ++i) { s1[i]=0.f; s2[i]=0.f; q1[i]=0.f; q2[i]=0.f; }
        #pragma unroll
        for (int m = 3; m <= 16; ++m) {       // sum/diff/squares once per col
            const float sm = a[m] + b[m];
            const float dm = a[m] - b[m];
            const float sq = sm * sm;
            const float dq = dm * dm;
            #pragma unroll
            for (int i = 0; i < 4; ++i) {     // output col i uses tap j = m-3-i
                const int j = m - 3 - i;
                if (j >= 0 && j < 11) {
                    const float wj = win.w[j];
                    s1[i] += wj * sm;
                    s2[i] += wj * dm;
                    q1[i] += wj * sq;
                    q2[i] += wj * dq;
                }
            }
        }
        // transposed store: word = st*STS + (4cb+i)*PITCH + r
        // one base VGPR, 16 imm-offset ds_write_b32
        const int wbase = (4 * cb) * PITCH + r;
        #pragma unroll
        for (int i = 0; i < 4; ++i) {
            hs[0 * STS + wbase + i * PITCH] = s1[i];
            hs[1 * STS + wbase + i * PITCH] = s2[i];
            hs[2 * STS + wbase + i * PITCH] = q1[i];
            hs[3 * STS + wbase + i * PITCH] = q2[i];
        }
    }
    __syncthreads();

    // ---- phase B: V-pass; thread = (col x, 8 output rows), reg sliding window ----
    const int x  = tid & 31;
    const int rg = tid >> 5;            // 0..7
    const int r0 = rg * 8;              // first owned output row (local)
    const float* __restrict__ cbase = &hs[x * PITCH + r0];

    float sum[4][8];
    #pragma unroll
    for (int st = 0; st < 4; ++st)
        #pragma unroll
        for (int k = 0; k < 8; ++k) sum[st][k] = 0.f;

    #pragma unroll
    for (int st = 0; st < 4; ++st) {
        float v[18];
        #pragma unroll
        for (int m = 0; m < 18; ++m)        // imm-offset b32 (ds_read2-pairable)
            v[m] = cbase[st * STS + m];
        #pragma unroll
        for (int m = 0; m < 18; ++m) {
            #pragma unroll
            for (int k = 0; k < 8; ++k) {   // output k uses tap j = m-k
                if (k >= m - 10 && k <= m)
                    sum[st][k] += win.w[m - k] * v[m];
            }
        }
    }

    float acc = 0.f;
    #pragma unroll
    for (int k = 0; k < 8; ++k) {
        const float S1 = sum[0][k];
        const float S2 = sum[1][k];
        const float Q1 = sum[2][k];
        const float Q2 = sum[3][k];
        const float s1q = S1 * S1;
        const float s2q = S2 * S2;
        const float A_  = 0.5f * (s1q + s2q);     // mu1^2 + mu2^2
        const float B_  = 0.5f * (s1q - s2q);     // 2 mu1 mu2
        const float sps = 0.5f * (Q1 + Q2) - A_;  // sig1^2 + sig2^2
        const float sxx = 0.5f * (Q1 - Q2) - B_;  // 2 sig12
        const float num = (B_ + C1v) * (sxx + C2v);
        const float den = (A_ + C1v) * (sps + C2v);
        acc += num * __builtin_amdgcn_rcpf(den);
    }

    // ---- block reduction ----
    #pragma unroll
    for (int off = 32; off > 0; off >>= 1)
        acc += __shfl_down(acc, off, 64);
    const int wv = tid >> 6;
    if ((tid & 63) == 0) wavesum[wv] = acc;
    __syncthreads();
    if (tid == 0) {
        const int bid = (blockIdx.z * gridDim.y + blockIdx.y) * gridDim.x + blockIdx.x;
        partial[bid] = wavesum[0] + wavesum[1] + wavesum[2] + wavesum[3];
    }
}

__global__ __launch_bounds__(256) void ssim_reduce_kernel(
        const float* __restrict__ partial,
        float* __restrict__ out,
        int nblk, double inv_n) {
    __shared__ double wsum[4];
    double s = 0.0;
    for (int i = threadIdx.x; i < nblk; i += 256)
        s += (double)partial[i];
    #pragma unroll
    for (int off = 32; off > 0; off >>= 1)
        s += __shfl_down(s, off, 64);
    const int wv = threadIdx.x >> 6;
    if ((threadIdx.x & 63) == 0) wsum[wv] = s;
    __syncthreads();
    if (threadIdx.x == 0) {
        const double tot = wsum[0] + wsum[1] + wsum[2] + wsum[3];
        out[0] = (float)(tot * inv_n);
    }
}

extern "C" void kernel_launch(void* const* d_in, const int* in_sizes, int n_in,
                              void* d_out, int out_size, void* d_ws, size_t ws_size,
                              hipStream_t stream) {
    const float* pred = (const float*)d_in[0];
    const float* targ = (const float*)d_in[1];
    float* out     = (float*)d_out;
    float* partial = (float*)d_ws;   // 16*8*48 = 6144 floats, all written

    Win win;
    {
        double v[11], s = 0.0;
        for (int i = 0; i < 11; ++i) {
            float d   = (float)i - 5.0f;
            float arg = -(d * d) / 4.5f;      // 2*sigma^2 = 4.5
            v[i] = exp((double)arg);
            s += v[i];
        }
        for (int i = 0; i < 11; ++i) win.w[i] = (float)(v[i] / s);
    }

    dim3 grid(IMG / TC, IMG / TB, NIMG);      // (16, 8, 48) = 6144 blocks
    ssim_kernel<<<grid, 256, 0, stream>>>(pred, targ, partial, win);

    const int nblk = (IMG / TC) * (IMG / TB) * NIMG;
    const double inv_n = 1.0 / ((double)NIMG * IMG * IMG);
    ssim_reduce_kernel<<<1, 256, 0, stream>>>(partial, out, nblk, inv_n);
}

// Round 10
// 61.460 us; speedup vs baseline: 2.1381x; 1.1565x over previous
//
#include <hip/hip_runtime.h>
#include <math.h>

#define IMG   512
#define NIMG  48
#define TB    64            // output tile rows
#define TC    32            // output tile cols
#define SR    74            // stat rows = TB + 10
#define PITCH 77            // odd pitch: bank = (13x+r) mod 32 bijective (R9-validated, 0 conflicts)
#define STS   (TC * PITCH)  // stat plane stride
#define C1v   1.0e-4f
#define C2v   9.0e-4f

struct Win { float w[11]; };

// R10: R9 proved the conflict-free transposed-b32 layout (0 conflicts). All
// pipes model at ~24us but we ran 65 -> latency/overlap-bound (Occ 36%).
// Changes: 512-thread blocks (4 blocks/CU x 8 waves = 32 waves/CU, 2x), phase B
// = (col, 4 rows)/thread (half the latency chain, ~35 live regs), phase A
// staging as sm/dm (28 regs, allocator stays <=64), float4 reduce tail.
__global__ __launch_bounds__(512, 4) void ssim_kernel(
        const float* __restrict__ pred,
        const float* __restrict__ targ,
        float* __restrict__ partial, Win win) {
    __shared__ float hs[4 * STS];
    __shared__ float wavesum[8];

    const int tid = threadIdx.x;
    const int n   = blockIdx.z;
    const int by  = blockIdx.y;
    const int bx  = blockIdx.x;
    const int y0  = by * TB;
    const int x0  = bx * TC;

    const float* __restrict__ P = pred + (size_t)n * IMG * IMG;
    const float* __restrict__ T = targ + (size_t)n * IMG * IMG;

    // ---- phase A: H-pass from global; unit = (stat row r, col-quad cb) ----
    #pragma unroll 1
    for (int u = tid; u < SR * 8; u += 512) {
        const int r  = u >> 3;
        const int cb = u & 7;
        const int gy = y0 - 5 + r;
        const bool yok = (gy >= 0) & (gy < IMG);
        const float* __restrict__ Prow = P + (long)gy * IMG;
        const float* __restrict__ Trow = T + (long)gy * IMG;

        float sm[14], dm[14];
        #pragma unroll
        for (int k = 0; k < 5; ++k) {
            // every 16B chunk is fully in-image or fully padding (R8-proven)
            const bool zero = (!yok) |
                              ((bx == 0)  & (cb + k <= 1)) |
                              ((bx == 15) & (cb + k >= 10));
            float4 p = make_float4(0.f, 0.f, 0.f, 0.f);
            float4 t = make_float4(0.f, 0.f, 0.f, 0.f);
            if (!zero) {
                const int gx = x0 + 4 * (cb + k - 2);
                p = *(const float4*)(Prow + gx);
                t = *(const float4*)(Trow + gx);
            }
            const float pv[4] = { p.x, p.y, p.z, p.w };
            const float tv[4] = { t.x, t.y, t.z, t.w };
            #pragma unroll
            for (int j = 0; j < 4; ++j) {
                const int w = 4 * k + j;          // window word 0..19
                if (w >= 3 && w <= 16) {          // only 3..16 are used
                    sm[w - 3] = pv[j] + tv[j];
                    dm[w - 3] = pv[j] - tv[j];
                }
            }
        }

        float s1[4], s2[4], q1[4], q2[4];
        #pragma unroll
        for (int i = 0; i < 4; ++i) { s1[i]=0.f; s2[i]=0.f; q1[i]=0.f; q2[i]=0.f; }
        #pragma unroll
        for (int m = 0; m < 14; ++m) {
            const float s  = sm[m];
            const float d  = dm[m];
            const float sq = s * s;
            const float dq = d * d;
            #pragma unroll
            for (int i = 0; i < 4; ++i) {         // col i uses tap j = m - i
                const int j = m - i;
                if (j >= 0 && j < 11) {
                    const float wj = win.w[j];
                    s1[i] += wj * s;
                    s2[i] += wj * d;
                    q1[i] += wj * sq;
                    q2[i] += wj * dq;
                }
            }
        }
        // transposed store: word = st*STS + (4cb+i)*PITCH + r  (2-way max = free)
        const int wbase = (4 * cb) * PITCH + r;
        #pragma unroll
        for (int i = 0; i < 4; ++i) {
            hs[0 * STS + wbase + i * PITCH] = s1[i];
            hs[1 * STS + wbase + i * PITCH] = s2[i];
            hs[2 * STS + wbase + i * PITCH] = q1[i];
            hs[3 * STS + wbase + i * PITCH] = q2[i];
        }
    }
    __syncthreads();

    // ---- phase B: V-pass; thread = (col x, 4 output rows), reg window ----
    const int x  = tid & 31;
    const int rg = tid >> 5;            // 0..15
    const int r0 = rg * 4;
    const float* __restrict__ cbase = &hs[x * PITCH + r0];

    float sum[4][4];
    #pragma unroll
    for (int st = 0; st < 4; ++st)
        #pragma unroll
        for (int k = 0; k < 4; ++k) sum[st][k] = 0.f;

    #pragma unroll
    for (int st = 0; st < 4; ++st) {
        float v[14];
        #pragma unroll
        for (int m = 0; m < 14; ++m)    // consecutive words -> ds_read2 pairs
            v[m] = cbase[st * STS + m];
        #pragma unroll
        for (int m = 0; m < 14; ++m) {
            #pragma unroll
            for (int k = 0; k < 4; ++k) {   // output k uses tap j = m - k
                if (k >= m - 10 && k <= m)
                    sum[st][k] += win.w[m - k] * v[m];
            }
        }
    }

    float acc = 0.f;
    #pragma unroll
    for (int k = 0; k < 4; ++k) {
        const float S1 = sum[0][k];
        const float S2 = sum[1][k];
        const float Q1 = sum[2][k];
        const float Q2 = sum[3][k];
        const float s1q = S1 * S1;
        const float s2q = S2 * S2;
        const float A_  = 0.5f * (s1q + s2q);     // mu1^2 + mu2^2
        const float B_  = 0.5f * (s1q - s2q);     // 2 mu1 mu2
        const float sps = 0.5f * (Q1 + Q2) - A_;  // sig1^2 + sig2^2
        const float sxx = 0.5f * (Q1 - Q2) - B_;  // 2 sig12
        const float num = (B_ + C1v) * (sxx + C2v);
        const float den = (A_ + C1v) * (sps + C2v);
        acc += num * __builtin_amdgcn_rcpf(den);
    }

    // ---- block reduction (8 waves) ----
    #pragma unroll
    for (int off = 32; off > 0; off >>= 1)
        acc += __shfl_down(acc, off, 64);
    const int wv = tid >> 6;
    if ((tid & 63) == 0) wavesum[wv] = acc;
    __syncthreads();
    if (tid == 0) {
        float s = 0.f;
        #pragma unroll
        for (int i = 0; i < 8; ++i) s += wavesum[i];
        const int bid = (blockIdx.z * gridDim.y + blockIdx.y) * gridDim.x + blockIdx.x;
        partial[bid] = s;
    }
}

__global__ __launch_bounds__(512) void ssim_reduce_kernel(
        const float* __restrict__ partial,
        float* __restrict__ out,
        int nchunk4, double inv_n) {
    __shared__ double wsum[8];
    const float4* __restrict__ p4 = (const float4*)partial;
    double s = 0.0;
    #pragma unroll 1
    for (int i = threadIdx.x; i < nchunk4; i += 512) {
        const float4 v = p4[i];
        s += (double)((v.x + v.y) + (v.z + v.w));
    }
    #pragma unroll
    for (int off = 32; off > 0; off >>= 1)
        s += __shfl_down(s, off, 64);
    const int wv = threadIdx.x >> 6;
    if ((threadIdx.x & 63) == 0) wsum[wv] = s;
    __syncthreads();
    if (threadIdx.x == 0) {
        double tot = 0.0;
        #pragma unroll
        for (int i = 0; i < 8; ++i) tot += wsum[i];
        out[0] = (float)(tot * inv_n);
    }
}

extern "C" void kernel_launch(void* const* d_in, const int* in_sizes, int n_in,
                              void* d_out, int out_size, void* d_ws, size_t ws_size,
                              hipStream_t stream) {
    const float* pred = (const float*)d_in[0];
    const float* targ = (const float*)d_in[1];
    float* out     = (float*)d_out;
    float* partial = (float*)d_ws;   // 16*8*48 = 6144 floats, all written

    Win win;
    {
        double v[11], s = 0.0;
        for (int i = 0; i < 11; ++i) {
            float d   = (float)i - 5.0f;
            float arg = -(d * d) / 4.5f;      // 2*sigma^2 = 4.5
            v[i] = exp((double)arg);
            s += v[i];
        }
        for (int i = 0; i < 11; ++i) win.w[i] = (float)(v[i] / s);
    }

    dim3 grid(IMG / TC, IMG / TB, NIMG);      // (16, 8, 48) = 6144 blocks
    ssim_kernel<<<grid, 512, 0, stream>>>(pred, targ, partial, win);

    const int nblk = (IMG / TC) * (IMG / TB) * NIMG;   // 6144 -> 1536 float4
    const double inv_n = 1.0 / ((double)NIMG * IMG * IMG);
    ssim_reduce_kernel<<<1, 512, 0, stream>>>(partial, out, nblk / 4, inv_n);
}

// Round 11
// 58.433 us; speedup vs baseline: 2.2489x; 1.0518x over previous
//
#include <hip/hip_runtime.h>
#include <math.h>

#define IMG   512
#define NIMG  48
#define TB    64            // output tile rows
#define TC    32            // output tile cols
#define SR    74            // stat rows = TB + 10
#define PITCH 77            // odd pitch: bank = (13x+r) mod 32 bijective (R9: 0 conflicts)
#define STS   (TC * PITCH)  // stat plane stride
#define C1v   1.0e-4f
#define C2v   9.0e-4f

struct Win { float w[11]; };

// R11: R10's VGPR=32 < ~44 live (phase A) is the third allocator-undershoot;
// spills go to AGPRs (invisible in VGPR_Count, pure VALU fat; WRITE_SIZE flat
// rules out scratch->HBM). Occupancy is wave-capped at 8 waves/SIMD which only
// needs VGPR<=64 -> free headroom. Changes:
//  1) __launch_bounds__(512,8): cap exactly 64 VGPR.
//  2) phase A streams chunk-by-chunk (peak live ~40).
//  3) phase B interleaves read->FMA (live ~22).
//  4) interior blocks (66%) skip all bounds logic via template<GUARD>.
template<bool GUARD>
__device__ __forceinline__ void phaseA_unit(
        float* __restrict__ hs,
        const float* __restrict__ P,
        const float* __restrict__ T,
        const Win& win, int bx, int y0, int x0, int u) {
    const int r  = u >> 3;
    const int cb = u & 7;
    const int gy = y0 - 5 + r;
    const float* __restrict__ Prow = P + (long)gy * IMG;
    const float* __restrict__ Trow = T + (long)gy * IMG;
    const bool yok = (!GUARD) || ((gy >= 0) & (gy < IMG));

    float s1[4], s2[4], q1[4], q2[4];
    #pragma unroll
    for (int i = 0; i < 4; ++i) { s1[i]=0.f; s2[i]=0.f; q1[i]=0.f; q2[i]=0.f; }

    // window words 0..19 in 5 aligned 16B chunks; words 3..16 are used.
    // Streaming: load chunk -> fold its words into the 16 accumulators -> reuse.
    #pragma unroll
    for (int k = 0; k < 5; ++k) {
        float4 p = make_float4(0.f, 0.f, 0.f, 0.f);
        float4 t = make_float4(0.f, 0.f, 0.f, 0.f);
        bool zero = false;
        if (GUARD)   // every 16B chunk is fully in-image or fully padding (R8-proven)
            zero = (!yok) | ((bx == 0)  & (cb + k <= 1))
                          | ((bx == 15) & (cb + k >= 10));
        if (!zero) {
            const int gx = x0 + 4 * (cb + k - 2);
            p = *(const float4*)(Prow + gx);
            t = *(const float4*)(Trow + gx);
        }
        const float pv[4] = { p.x, p.y, p.z, p.w };
        const float tv[4] = { t.x, t.y, t.z, t.w };
        #pragma unroll
        for (int j4 = 0; j4 < 4; ++j4) {
            const int w = 4 * k + j4;
            if (w >= 3 && w <= 16) {
                const float sm = pv[j4] + tv[j4];
                const float dm = pv[j4] - tv[j4];
                const float sq = sm * sm;
                const float dq = dm * dm;
                #pragma unroll
                for (int i = 0; i < 4; ++i) {     // col i uses tap j = w-3-i
                    const int j = w - 3 - i;
                    if (j >= 0 && j < 11) {
                        const float wj = win.w[j];
                        s1[i] += wj * sm;
                        s2[i] += wj * dm;
                        q1[i] += wj * sq;
                        q2[i] += wj * dq;
                    }
                }
            }
        }
    }
    // transposed store: word = st*STS + (4cb+i)*PITCH + r  (2 lanes/bank = free)
    const int wbase = (4 * cb) * PITCH + r;
    #pragma unroll
    for (int i = 0; i < 4; ++i) {
        hs[0 * STS + wbase + i * PITCH] = s1[i];
        hs[1 * STS + wbase + i * PITCH] = s2[i];
        hs[2 * STS + wbase + i * PITCH] = q1[i];
        hs[3 * STS + wbase + i * PITCH] = q2[i];
    }
}

__global__ __launch_bounds__(512, 8) void ssim_kernel(
        const float* __restrict__ pred,
        const float* __restrict__ targ,
        float* __restrict__ partial, Win win) {
    __shared__ float hs[4 * STS];
    __shared__ float wavesum[8];

    const int tid = threadIdx.x;
    const int n   = blockIdx.z;
    const int by  = blockIdx.y;
    const int bx  = blockIdx.x;
    const int y0  = by * TB;
    const int x0  = bx * TC;

    const float* __restrict__ P = pred + (size_t)n * IMG * IMG;
    const float* __restrict__ T = targ + (size_t)n * IMG * IMG;

    // ---- phase A: H-pass from global; unit = (stat row r, col-quad cb) ----
    const bool guard = (bx == 0) | (bx == 15) | (by == 0) | (by == (IMG / TB - 1));
    if (guard) {
        #pragma unroll 1
        for (int u = tid; u < SR * 8; u += 512)
            phaseA_unit<true >(hs, P, T, win, bx, y0, x0, u);
    } else {
        #pragma unroll 1
        for (int u = tid; u < SR * 8; u += 512)
            phaseA_unit<false>(hs, P, T, win, bx, y0, x0, u);
    }
    __syncthreads();

    // ---- phase B: V-pass; thread = (col x, 4 output rows), interleaved ----
    const int x  = tid & 31;
    const int rg = tid >> 5;            // 0..15
    const int r0 = rg * 4;
    const float* __restrict__ cbase = &hs[x * PITCH + r0];

    float sum[4][4];
    #pragma unroll
    for (int st = 0; st < 4; ++st)
        #pragma unroll
        for (int k = 0; k < 4; ++k) sum[st][k] = 0.f;

    #pragma unroll
    for (int st = 0; st < 4; ++st) {
        const float* __restrict__ cp = cbase + st * STS;
        #pragma unroll
        for (int m = 0; m < 14; ++m) {  // consecutive words -> ds_read2 pairs
            const float v = cp[m];
            #pragma unroll
            for (int k = 0; k < 4; ++k) {   // output k uses tap j = m - k
                const int j = m - k;
                if (j >= 0 && j < 11)
                    sum[st][k] += win.w[j] * v;
            }
        }
    }

    float acc = 0.f;
    #pragma unroll
    for (int k = 0; k < 4; ++k) {
        const float S1 = sum[0][k];
        const float S2 = sum[1][k];
        const float Q1 = sum[2][k];
        const float Q2 = sum[3][k];
        const float s1q = S1 * S1;
        const float s2q = S2 * S2;
        const float A_  = 0.5f * (s1q + s2q);     // mu1^2 + mu2^2
        const float B_  = 0.5f * (s1q - s2q);     // 2 mu1 mu2
        const float sps = 0.5f * (Q1 + Q2) - A_;  // sig1^2 + sig2^2
        const float sxx = 0.5f * (Q1 - Q2) - B_;  // 2 sig12
        const float num = (B_ + C1v) * (sxx + C2v);
        const float den = (A_ + C1v) * (sps + C2v);
        acc += num * __builtin_amdgcn_rcpf(den);
    }

    // ---- block reduction (8 waves) ----
    #pragma unroll
    for (int off = 32; off > 0; off >>= 1)
        acc += __shfl_down(acc, off, 64);
    const int wv = tid >> 6;
    if ((tid & 63) == 0) wavesum[wv] = acc;
    __syncthreads();
    if (tid == 0) {
        float s = 0.f;
        #pragma unroll
        for (int i = 0; i < 8; ++i) s += wavesum[i];
        const int bid = (blockIdx.z * gridDim.y + blockIdx.y) * gridDim.x + blockIdx.x;
        partial[bid] = s;
    }
}

__global__ __launch_bounds__(512) void ssim_reduce_kernel(
        const float* __restrict__ partial,
        float* __restrict__ out,
        int nchunk4, double inv_n) {
    __shared__ double wsum[8];
    const float4* __restrict__ p4 = (const float4*)partial;
    double s = 0.0;
    #pragma unroll 1
    for (int i = threadIdx.x; i < nchunk4; i += 512) {
        const float4 v = p4[i];
        s += (double)((v.x + v.y) + (v.z + v.w));
    }
    #pragma unroll
    for (int off = 32; off > 0; off >>= 1)
        s += __shfl_down(s, off, 64);
    const int wv = threadIdx.x >> 6;
    if ((threadIdx.x & 63) == 0) wsum[wv] = s;
    __syncthreads();
    if (threadIdx.x == 0) {
        double tot = 0.0;
        #pragma unroll
        for (int i = 0; i < 8; ++i) tot += wsum[i];
        out[0] = (float)(tot * inv_n);
    }
}

extern "C" void kernel_launch(void* const* d_in, const int* in_sizes, int n_in,
                              void* d_out, int out_size, void* d_ws, size_t ws_size,
                              hipStream_t stream) {
    const float* pred = (const float*)d_in[0];
    const float* targ = (const float*)d_in[1];
    float* out     = (float*)d_out;
    float* partial = (float*)d_ws;   // 16*8*48 = 6144 floats, all written

    Win win;
    {
        double v[11], s = 0.0;
        for (int i = 0; i < 11; ++i) {
            float d   = (float)i - 5.0f;
            float arg = -(d * d) / 4.5f;      // 2*sigma^2 = 4.5
            v[i] = exp((double)arg);
            s += v[i];
        }
        for (int i = 0; i < 11; ++i) win.w[i] = (float)(v[i] / s);
    }

    dim3 grid(IMG / TC, IMG / TB, NIMG);      // (16, 8, 48) = 6144 blocks
    ssim_kernel<<<grid, 512, 0, stream>>>(pred, targ, partial, win);

    const int nblk = (IMG / TC) * (IMG / TB) * NIMG;   // 6144 -> 1536 float4
    const double inv_n = 1.0 / ((double)NIMG * IMG * IMG);
    ssim_reduce_kernel<<<1, 512, 0, stream>>>(partial, out, nblk / 4, inv_n);
}

// Round 12
// 55.098 us; speedup vs baseline: 2.3850x; 1.0605x over previous
//
#include <hip/hip_runtime.h>
#include <math.h>

#define IMG   512
#define NIMG  48
#define TB    64            // output tile rows
#define TC    32            // output tile cols
#define SR    74            // stat rows = TB + 10
#define PITCH 77            // odd pitch (R9-validated bijective-bank construction)
#define STS   (TC * PITCH)  // float2 elements per plane
#define C1v   1.0e-4f
#define C2v   9.0e-4f

struct Win { float w[11]; };

// R12: cross-round invariant dur*VALUBusy ~= 51us (R7/R9/R10/R11) + source
// count ~147 inst/output says the gfx94x VALUBusy formula double-counts on
// SIMD-32; true VALU ~44%, co-binding pipe is LDS (~596 wave-b32/block ~60%).
// Fix: paired-stat b64 LDS. float2 hs2[2][x][r]: plane0=(s1,s2), plane1=(q1,q2).
//  writes: 8 ds_write_b64/unit, bank-pair a=(13(4cb+i)+r) mod 16 -> 4 lanes/pair
//          = wave64-b64 minimum (free).
//  reads: 28 ds_read_b64/thread (ds_read2_b64-pairable), lanes x*13 mod 16
//         bijective -> minimum (free).
// Same construction R9 proved at b32 -- NOT the opaque strided-b128 pattern.
template<bool GUARD>
__device__ __forceinline__ void phaseA_unit(
        float2* __restrict__ hs2,
        const float* __restrict__ P,
        const float* __restrict__ T,
        const Win& win, int bx, int y0, int x0, int u) {
    const int r  = u >> 3;
    const int cb = u & 7;
    const int gy = y0 - 5 + r;
    const float* __restrict__ Prow = P + (long)gy * IMG;
    const float* __restrict__ Trow = T + (long)gy * IMG;
    const bool yok = (!GUARD) || ((gy >= 0) & (gy < IMG));

    float s1[4], s2[4], q1[4], q2[4];
    #pragma unroll
    for (int i = 0; i < 4; ++i) { s1[i]=0.f; s2[i]=0.f; q1[i]=0.f; q2[i]=0.f; }

    // window words 0..19 in 5 aligned 16B chunks; words 3..16 used.
    #pragma unroll
    for (int k = 0; k < 5; ++k) {
        float4 p = make_float4(0.f, 0.f, 0.f, 0.f);
        float4 t = make_float4(0.f, 0.f, 0.f, 0.f);
        bool zero = false;
        if (GUARD)   // every 16B chunk fully in-image or fully padding (R8-proven)
            zero = (!yok) | ((bx == 0)  & (cb + k <= 1))
                          | ((bx == 15) & (cb + k >= 10));
        if (!zero) {
            const int gx = x0 + 4 * (cb + k - 2);
            p = *(const float4*)(Prow + gx);
            t = *(const float4*)(Trow + gx);
        }
        const float pv[4] = { p.x, p.y, p.z, p.w };
        const float tv[4] = { t.x, t.y, t.z, t.w };
        #pragma unroll
        for (int j4 = 0; j4 < 4; ++j4) {
            const int w = 4 * k + j4;
            if (w >= 3 && w <= 16) {
                const float sm = pv[j4] + tv[j4];
                const float dm = pv[j4] - tv[j4];
                const float sq = sm * sm;
                const float dq = dm * dm;
                #pragma unroll
                for (int i = 0; i < 4; ++i) {     // col i uses tap j = w-3-i
                    const int j = w - 3 - i;
                    if (j >= 0 && j < 11) {
                        const float wj = win.w[j];
                        s1[i] += wj * sm;
                        s2[i] += wj * dm;
                        q1[i] += wj * sq;
                        q2[i] += wj * dq;
                    }
                }
            }
        }
    }
    // paired b64 stores: elem = plane*STS + (4cb+i)*PITCH + r
    const int ebase = (4 * cb) * PITCH + r;
    #pragma unroll
    for (int i = 0; i < 4; ++i) {
        hs2[ebase + i * PITCH]       = make_float2(s1[i], s2[i]);
        hs2[STS + ebase + i * PITCH] = make_float2(q1[i], q2[i]);
    }
}

__global__ __launch_bounds__(512, 8) void ssim_kernel(
        const float* __restrict__ pred,
        const float* __restrict__ targ,
        float* __restrict__ partial, Win win) {
    __shared__ float2 hs2[2 * STS];
    __shared__ float wavesum[8];

    const int tid = threadIdx.x;
    const int n   = blockIdx.z;
    const int by  = blockIdx.y;
    const int bx  = blockIdx.x;
    const int y0  = by * TB;
    const int x0  = bx * TC;

    const float* __restrict__ P = pred + (size_t)n * IMG * IMG;
    const float* __restrict__ T = targ + (size_t)n * IMG * IMG;

    // ---- phase A: H-pass from global; unit = (stat row r, col-quad cb) ----
    const bool guard = (bx == 0) | (bx == 15) | (by == 0) | (by == (IMG / TB - 1));
    if (guard) {
        #pragma unroll 1
        for (int u = tid; u < SR * 8; u += 512)
            phaseA_unit<true >(hs2, P, T, win, bx, y0, x0, u);
    } else {
        #pragma unroll 1
        for (int u = tid; u < SR * 8; u += 512)
            phaseA_unit<false>(hs2, P, T, win, bx, y0, x0, u);
    }
    __syncthreads();

    // ---- phase B: V-pass; thread = (col x, 4 output rows), b64 reads ----
    const int x  = tid & 31;
    const int rg = tid >> 5;            // 0..15
    const int r0 = rg * 4;
    const float2* __restrict__ csd = &hs2[x * PITCH + r0];         // (s1,s2)
    const float2* __restrict__ cqq = &hs2[STS + x * PITCH + r0];   // (q1,q2)

    float sum[4][4];
    #pragma unroll
    for (int st = 0; st < 4; ++st)
        #pragma unroll
        for (int k = 0; k < 4; ++k) sum[st][k] = 0.f;

    #pragma unroll
    for (int m = 0; m < 14; ++m) {      // consecutive elems -> ds_read2_b64
        const float2 sd = csd[m];
        const float2 qq = cqq[m];
        #pragma unroll
        for (int k = 0; k < 4; ++k) {   // output k uses tap j = m - k
            const int j = m - k;
            if (j >= 0 && j < 11) {
                const float wj = win.w[j];
                sum[0][k] += wj * sd.x;
                sum[1][k] += wj * sd.y;
                sum[2][k] += wj * qq.x;
                sum[3][k] += wj * qq.y;
            }
        }
    }

    float acc = 0.f;
    #pragma unroll
    for (int k = 0; k < 4; ++k) {
        const float S1 = sum[0][k];
        const float S2 = sum[1][k];
        const float Q1 = sum[2][k];
        const float Q2 = sum[3][k];
        const float s1q = S1 * S1;
        const float s2q = S2 * S2;
        const float A_  = 0.5f * (s1q + s2q);     // mu1^2 + mu2^2
        const float B_  = 0.5f * (s1q - s2q);     // 2 mu1 mu2
        const float sps = 0.5f * (Q1 + Q2) - A_;  // sig1^2 + sig2^2
        const float sxx = 0.5f * (Q1 - Q2) - B_;  // 2 sig12
        const float num = (B_ + C1v) * (sxx + C2v);
        const float den = (A_ + C1v) * (sps + C2v);
        acc += num * __builtin_amdgcn_rcpf(den);
    }

    // ---- block reduction (8 waves) ----
    #pragma unroll
    for (int off = 32; off > 0; off >>= 1)
        acc += __shfl_down(acc, off, 64);
    const int wv = tid >> 6;
    if ((tid & 63) == 0) wavesum[wv] = acc;
    __syncthreads();
    if (tid == 0) {
        float s = 0.f;
        #pragma unroll
        for (int i = 0; i < 8; ++i) s += wavesum[i];
        const int bid = (blockIdx.z * gridDim.y + blockIdx.y) * gridDim.x + blockIdx.x;
        partial[bid] = s;
    }
}

__global__ __launch_bounds__(512) void ssim_reduce_kernel(
        const float* __restrict__ partial,
        float* __restrict__ out,
        int nchunk4, double inv_n) {
    __shared__ double wsum[8];
    const float4* __restrict__ p4 = (const float4*)partial;
    double s = 0.0;
    #pragma unroll 1
    for (int i = threadIdx.x; i < nchunk4; i += 512) {
        const float4 v = p4[i];
        s += (double)((v.x + v.y) + (v.z + v.w));
    }
    #pragma unroll
    for (int off = 32; off > 0; off >>= 1)
        s += __shfl_down(s, off, 64);
    const int wv = threadIdx.x >> 6;
    if ((threadIdx.x & 63) == 0) wsum[wv] = s;
    __syncthreads();
    if (threadIdx.x == 0) {
        double tot = 0.0;
        #pragma unroll
        for (int i = 0; i < 8; ++i) tot += wsum[i];
        out[0] = (float)(tot * inv_n);
    }
}

extern "C" void kernel_launch(void* const* d_in, const int* in_sizes, int n_in,
                              void* d_out, int out_size, void* d_ws, size_t ws_size,
                              hipStream_t stream) {
    const float* pred = (const float*)d_in[0];
    const float* targ = (const float*)d_in[1];
    float* out     = (float*)d_out;
    float* partial = (float*)d_ws;   // 16*8*48 = 6144 floats, all written

    Win win;
    {
        double v[11], s = 0.0;
        for (int i = 0; i < 11; ++i) {
            float d   = (float)i - 5.0f;
            float arg = -(d * d) / 4.5f;      // 2*sigma^2 = 4.5
            v[i] = exp((double)arg);
            s += v[i];
        }
        for (int i = 0; i < 11; ++i) win.w[i] = (float)(v[i] / s);
    }

    dim3 grid(IMG / TC, IMG / TB, NIMG);      // (16, 8, 48) = 6144 blocks
    ssim_kernel<<<grid, 512, 0, stream>>>(pred, targ, partial, win);

    const int nblk = (IMG / TC) * (IMG / TB) * NIMG;   // 6144 -> 1536 float4
    const double inv_n = 1.0 / ((double)NIMG * IMG * IMG);
    ssim_reduce_kernel<<<1, 512, 0, stream>>>(partial, out, nblk / 4, inv_n);
}